// Round 14
// baseline (3835.769 us; speedup 1.0000x reference)
//
#include <hip/hip_runtime.h>
#include <hip/hip_bf16.h>

#define B_ 2
#define T_ 32768
#define CH_ 128
#define EC_ 512
#define ATOM_ 2048
#define FBK_ 512

typedef __attribute__((ext_vector_type(8))) short s16x8;
typedef __attribute__((ext_vector_type(8))) _Float16 f16x8;
typedef __attribute__((ext_vector_type(4))) float f32x4;

__device__ __forceinline__ f16x8 ldh8(const _Float16* p) {
    union { s16x8 s; f16x8 h; } u; u.s = *(const s16x8*)p; return u.h;
}

// ---------------- MFMA filter bank: x[b,1,T] -> spec16[b][t][band] f16 ----------------
__global__ void __launch_bounds__(256) k_fbm(const float* __restrict__ x,
        const _Float16* __restrict__ Wfb, _Float16* __restrict__ spec16) {
    __shared__ _Float16 XA[128][72];
    __shared__ float xw[640];
    int tid = threadIdx.x;
    int lane = tid & 63;
    int wv = tid >> 6, wm = wv >> 1, wn = wv & 1;
    int ln15 = lane & 15, kh = lane >> 4;
    int t0 = blockIdx.x * 128;
    int b = blockIdx.y;

    for (int i = tid; i < 640; i += 256) {
        int g = t0 - 256 + i;
        xw[i] = (g >= 0 && g < T_) ? x[(size_t)b*T_ + g] : 0.f;
    }

    f32x4 acc[4][4];
    f32x4 zero = {0.f,0.f,0.f,0.f};
#pragma unroll
    for (int m = 0; m < 4; ++m)
#pragma unroll
        for (int n = 0; n < 4; ++n) acc[m][n] = zero;

    for (int c = 0; c < 8; ++c) {
        int k0 = c*64;
        __syncthreads();               // xw ready on c==0; XA WAR on c>0
#pragma unroll
        for (int q = 0; q < 4; ++q) {
            int idx = tid + q*256;
            int r = idx >> 3, ko = idx & 7;
            int base = r + k0 + ko*8;
            f16x8 v;
#pragma unroll
            for (int j = 0; j < 8; ++j) v[j] = (_Float16)xw[base + j];
            union { f16x8 h; s16x8 s; } u; u.h = v;
            *(s16x8*)&XA[r][ko*8] = u.s;
        }
        __syncthreads();
#pragma unroll
        for (int kt = 0; kt < 2; ++kt) {
            f16x8 af[4], bf[4];
#pragma unroll
            for (int m = 0; m < 4; ++m) af[m] = ldh8(&XA[wm*64+m*16+ln15][kt*32+kh*8]);
#pragma unroll
            for (int n = 0; n < 4; ++n)
                bf[n] = ldh8(Wfb + (size_t)(wn*64+n*16+ln15)*FBK_ + k0 + kt*32 + kh*8);
#pragma unroll
            for (int m = 0; m < 4; ++m)
#pragma unroll
                for (int n = 0; n < 4; ++n)
                    acc[m][n] = __builtin_amdgcn_mfma_f32_16x16x32_f16(af[m], bf[n], acc[m][n], 0,0,0);
        }
    }
#pragma unroll
    for (int mf = 0; mf < 4; ++mf)
#pragma unroll
        for (int nf = 0; nf < 4; ++nf) {
            int band = wn*64 + nf*16 + ln15;
#pragma unroll
            for (int j = 0; j < 4; ++j) {
                int tl = wm*64 + mf*16 + kh*4 + j;
                spec16[((size_t)b*T_ + t0 + tl)*CH_ + band] = (_Float16)acc[mf][nf][j];
            }
        }
}

// ---------------- weight prep ----------------
__global__ void k_pw7(const float* __restrict__ w, _Float16* __restrict__ W7) {
    int i = blockIdx.x*256+threadIdx.x;
    if (i >= 7*16384) return;
    int k = i / 16384, r = i % 16384; int co = r >> 7, ci = r & 127;
    W7[i] = (_Float16)w[(co*CH_+ci)*7 + k];
}
__global__ void k_pwd(const float* __restrict__ w, _Float16* __restrict__ Wd) {
    int i = blockIdx.x*256+threadIdx.x;
    if (i >= 7*3*16384) return;
    int st = i / 49152, r = i % 49152; int k = r / 16384, r2 = r % 16384;
    int co = r2 >> 7, ci = r2 & 127;
    Wd[i] = (_Float16)w[((size_t)(st*CH_+co)*CH_+ci)*3 + k];
}
__global__ void k_cast(const float* __restrict__ in, _Float16* __restrict__ out, int n) {
    int i = blockIdx.x*256+threadIdx.x;
    if (i < n) out[i] = (_Float16)in[i];
}
__global__ void k_zero(float* __restrict__ p, int n) {
    int i = blockIdx.x*256+threadIdx.x;
    if (i < n) p[i] = 0.f;
}

// ---------------- fused MFMA conv block (weights direct from global/L2) ----------------
template<int NTAP, bool NORM, bool PW, bool LRELU, bool RELU, bool STATS>
__global__ void __launch_bounds__(256) k_cv(
        const _Float16* __restrict__ in, const _Float16* __restrict__ W,
        const float* __restrict__ bias, const _Float16* __restrict__ Wp_,
        const float* __restrict__ pbias, const float* __restrict__ stats_in,
        const float* __restrict__ g, const float* __restrict__ bb,
        float* __restrict__ stats_out, _Float16* __restrict__ outp,
        int dil, int ostride) {
    __shared__ _Float16 XT[128][136];
    __shared__ _Float16 Y1[PW?128:1][PW?136:1];
    __shared__ float AffA[NORM?128:1], AffB[NORM?128:1];

    int tid = threadIdx.x;
    int lane = tid & 63;
    int wv = tid >> 6, wm = wv >> 1, wn = wv & 1;
    int ln15 = lane & 15, kh = lane >> 4;
    int t0 = blockIdx.x * 128;
    int nch = blockIdx.y;
    int b = blockIdx.z;
    int ncol0 = nch * 128;
    const _Float16* inb = in + (size_t)b*T_*CH_;
    const _Float16* W_eff = W + (size_t)ncol0*CH_;
    const float* bias_eff = bias + ncol0;

    if (NORM) {
        if (tid < 128) {
            const float invN = 1.f/(float)(B_*T_);
            float s1 = stats_in[tid], s2 = stats_in[128+tid];
            float m = s1*invN, var = s2*invN - m*m;
            float A = rsqrtf(var + 1e-5f) * g[tid];
            AffA[tid] = A; AffB[tid] = bb[tid] - m*A;
        }
    }

    f32x4 acc[4][4];
    f32x4 zero = {0.f,0.f,0.f,0.f};
#pragma unroll
    for (int m = 0; m < 4; ++m)
#pragma unroll
        for (int n = 0; n < 4; ++n) acc[m][n] = zero;

    for (int tap = 0; tap < NTAP; ++tap) {
        int tp = tap;
        if (PW) tp = (tap==0) ? 0 : ((tap==1) ? 2 : 1);   // center tap LAST (kept for residual)
        int off = (tp - NTAP/2)*dil;
        const _Float16* Wt = W_eff + (size_t)tp*CH_*CH_;
        __syncthreads();               // AffA ready (tap0) / XT WAR (tap>0)
#pragma unroll
        for (int q = 0; q < 8; ++q) {
            int idx = tid + q*256;
            int lt = idx >> 4, ck = idx & 15;
            int gt = t0 + lt + off;
            s16x8 v = {0,0,0,0,0,0,0,0};
            bool valid = (gt >= 0 && gt < T_);
            if (valid) {
                v = *(const s16x8*)(inb + (size_t)gt*CH_ + ck*8);
                if (NORM) {
                    union {s16x8 s; f16x8 h;} u; u.s = v;
                    f16x8 r;
#pragma unroll
                    for (int j = 0; j < 8; ++j) {
                        float f = (float)u.h[j];
                        f = fmaf(f, AffA[ck*8+j], AffB[ck*8+j]);
                        r[j] = (_Float16)f;
                    }
                    union {f16x8 h; s16x8 s;} w2; w2.h = r; v = w2.s;
                }
            }
            *(s16x8*)&XT[lt][ck*8] = v;
        }
        __syncthreads();
#pragma unroll
        for (int kt = 0; kt < 4; ++kt) {
            f16x8 af[4], bf[4];
#pragma unroll
            for (int m = 0; m < 4; ++m) af[m] = ldh8(&XT[wm*64+m*16+ln15][kt*32+kh*8]);
#pragma unroll
            for (int n = 0; n < 4; ++n)
                bf[n] = ldh8(Wt + (size_t)(wn*64+n*16+ln15)*CH_ + kt*32 + kh*8);
#pragma unroll
            for (int m = 0; m < 4; ++m)
#pragma unroll
                for (int n = 0; n < 4; ++n)
                    acc[m][n] = __builtin_amdgcn_mfma_f32_16x16x32_f16(af[m], bf[n], acc[m][n], 0,0,0);
        }
    }

    if (PW) {
#pragma unroll
        for (int mf = 0; mf < 4; ++mf)
#pragma unroll
            for (int nf = 0; nf < 4; ++nf) {
                int co = wn*64 + nf*16 + ln15;
                float bv = bias_eff[co];
#pragma unroll
                for (int j = 0; j < 4; ++j) {
                    int tl = wm*64 + mf*16 + kh*4 + j;
                    Y1[tl][co] = (_Float16)(acc[mf][nf][j] + bv);
                }
            }
#pragma unroll
        for (int m = 0; m < 4; ++m)
#pragma unroll
            for (int n = 0; n < 4; ++n) acc[m][n] = zero;
        __syncthreads();
#pragma unroll
        for (int kt = 0; kt < 4; ++kt) {
            f16x8 af[4], bf[4];
#pragma unroll
            for (int m = 0; m < 4; ++m) af[m] = ldh8(&Y1[wm*64+m*16+ln15][kt*32+kh*8]);
#pragma unroll
            for (int n = 0; n < 4; ++n)
                bf[n] = ldh8(Wp_ + (size_t)(wn*64+n*16+ln15)*CH_ + kt*32 + kh*8);
#pragma unroll
            for (int m = 0; m < 4; ++m)
#pragma unroll
                for (int n = 0; n < 4; ++n)
                    acc[m][n] = __builtin_amdgcn_mfma_f32_16x16x32_f16(af[m], bf[n], acc[m][n], 0,0,0);
        }
    }

#pragma unroll
    for (int nf = 0; nf < 4; ++nf) {
        int co = wn*64 + nf*16 + ln15;
        float bfin = PW ? pbias[co] : bias_eff[co];
        float s = 0.f, s2 = 0.f;
#pragma unroll
        for (int mf = 0; mf < 4; ++mf) {
#pragma unroll
            for (int j = 0; j < 4; ++j) {
                int tl = wm*64 + mf*16 + kh*4 + j;
                float v = acc[mf][nf][j] + bfin;
                if (PW) v += (float)XT[tl][co];    // residual = normalized center tile
                if (LRELU) v = v >= 0.f ? v : 0.2f*v;
                if (RELU)  v = fmaxf(v, 0.f);
                outp[((size_t)b*T_ + t0 + tl)*ostride + ncol0 + co] = (_Float16)v;
                if (STATS) { s += v; s2 += v*v; }
            }
        }
        if (STATS) {
            s  += __shfl_down(s, 16);  s  += __shfl_down(s, 32);
            s2 += __shfl_down(s2, 16); s2 += __shfl_down(s2, 32);
            if (kh == 0) {
                atomicAdd(&stats_out[co], s);
                atomicAdd(&stats_out[128+co], s2);
            }
        }
    }
}

// ---------------- transpose static_dict [512][2048] fp32 -> At [2048][512] f16 ----------------
__global__ void k_tr_at(const float* __restrict__ sd, _Float16* __restrict__ At) {
    __shared__ float tile[32][33];
    int tau0 = blockIdx.x*32;
    int c0 = blockIdx.y*32;
    int tx = threadIdx.x, ty = threadIdx.y;
#pragma unroll
    for (int j = 0; j < 4; ++j)
        tile[ty+j*8][tx] = sd[(size_t)(c0+ty+j*8)*ATOM_ + tau0 + tx];
    __syncthreads();
#pragma unroll
    for (int j = 0; j < 4; ++j)
        At[(size_t)(tau0+ty+j*8)*EC_ + c0 + tx] = (_Float16)tile[tx][ty+j*8];
}

// ---------------- dictionary conv: enc-in-registers, barrier-free tau loop (256 thr) ------
// block = (s-tile 128, c-chunk 64, b, tau-half). 4 waves: ws=wv&1 (s half),
// wt_g = th*2 + (wv>>1) in 0..3 (tau quarter of each 128-tau tile).
// For each of 16 tau-tiles: 16 MFMAs (At B-frags straight from L2), anti-diag into pt.
// NOTE: 256-thread block + (256,1) — 512-thread small-LDS builds got reg-capped to 40
// VGPRs and spilled (r10/r13); 256-thread kernels consistently allocate 88-152 regs.
__global__ void __launch_bounds__(256, 1) k_gemm(const _Float16* __restrict__ At,
                                                 const _Float16* __restrict__ enc,
                                                 float* __restrict__ opart) {
    __shared__ float pt[2176];
    int tid = threadIdx.x;
    int lane = tid & 63;
    int wv = tid >> 6;        // 0..3
    int ws = wv & 1;
    int wt = wv >> 1;         // 0..1
    int sT = blockIdx.x;
    int cc = blockIdx.y;
    int zb = blockIdx.z;
    int b  = zb >> 1;
    int th = zb & 1;
    int wt_g = th*2 + wt;     // 0..3
    int s0 = sT*128;
    int c0 = cc*64;
    int ln15 = lane & 15, kh = lane >> 4;

    for (int i = tid; i < 2176; i += 256) pt[i] = 0.f;

    // persistent enc A-fragments (32 VGPRs): rows s0+ws*64+m*16+ln15, k = c0+kk*32+kh*8
    f16x8 pa[4][2];
    const _Float16* Ep = enc + ((size_t)b*T_ + s0 + ws*64 + ln15)*EC_ + c0 + kh*8;
#pragma unroll
    for (int m = 0; m < 4; ++m)
#pragma unroll
        for (int kk = 0; kk < 2; ++kk)
            pa[m][kk] = ldh8(Ep + (size_t)m*16*EC_ + kk*32);

    __syncthreads();   // pt zeroed

    f32x4 acc[4][2];
    f32x4 zero = {0.f,0.f,0.f,0.f};
    const _Float16* Bp = At + ((size_t)(wt_g*32 + ln15))*EC_ + c0 + kh*8;

    for (int tl = 0; tl < 16; ++tl) {
        // B-frags for n=0,1 x kk=0,1 (At rows wt_g*32 + n*16 + ln15)
        f16x8 b00 = ldh8(Bp);
        f16x8 b10 = ldh8(Bp + (size_t)16*EC_);
        f16x8 b01 = ldh8(Bp + 32);
        f16x8 b11 = ldh8(Bp + (size_t)16*EC_ + 32);
#pragma unroll
        for (int m = 0; m < 4; ++m) {
            acc[m][0] = __builtin_amdgcn_mfma_f32_16x16x32_f16(pa[m][0], b00, zero, 0,0,0);
            acc[m][1] = __builtin_amdgcn_mfma_f32_16x16x32_f16(pa[m][0], b10, zero, 0,0,0);
        }
#pragma unroll
        for (int m = 0; m < 4; ++m) {
            acc[m][0] = __builtin_amdgcn_mfma_f32_16x16x32_f16(pa[m][1], b01, acc[m][0], 0,0,0);
            acc[m][1] = __builtin_amdgcn_mfma_f32_16x16x32_f16(pa[m][1], b11, acc[m][1], 0,0,0);
        }
        // anti-diag: t_local = (ws*64 + m*16 + kh*4 + j) + (tl*128 + wt_g*32 + n*16 + ln15)
        int base = tl*128 + wt_g*32 + ws*64 + kh*4 + ln15;
#pragma unroll
        for (int mn = 0; mn <= 4; ++mn) {
#pragma unroll
            for (int j = 0; j < 4; ++j) {
                float v = 0.f;
#pragma unroll
                for (int m = 0; m < 4; ++m) {
                    int n = mn - m;
                    if (n >= 0 && n < 2) v += acc[m][n][j];
                }
                unsafeAtomicAdd(&pt[base + mn*16 + j], v);
            }
        }
        Bp += (size_t)128*EC_;
    }
    __syncthreads();
    float* op = opart + ((size_t)cc*B_ + b)*T_;
    for (int i = tid; i < 2175; i += 256) {
        int t = s0 + i;
        if (t < T_) unsafeAtomicAdd(&op[t], pt[i]);
    }
}

// ---------------- reduce the 8 c-chunk partial planes ----------------
__global__ void k_red(const float* __restrict__ opart, float* __restrict__ out) {
    int i = blockIdx.x*256 + threadIdx.x;   // over B*T
    float s = 0.f;
#pragma unroll
    for (int p = 0; p < 8; ++p) s += opart[(size_t)p*B_*T_ + i];
    out[i] = s;
}

__global__ void k_fill(float* __restrict__ out, float val) {
    out[blockIdx.x*256 + threadIdx.x] = val;
}

extern "C" void kernel_launch(void* const* d_in, const int* in_sizes, int n_in,
                              void* d_out, int out_size, void* d_ws, size_t ws_size,
                              hipStream_t stream) {
    const float* x       = (const float*)d_in[0];
    const float* fb_w    = (const float*)d_in[1];
    const float* conv0_w = (const float*)d_in[2];
    const float* conv0_b = (const float*)d_in[3];
    const float* bn0_g   = (const float*)d_in[4];
    const float* bn0_b   = (const float*)d_in[5];
    const float* dil_w   = (const float*)d_in[6];
    const float* dil_b   = (const float*)d_in[7];
    const float* pw_w    = (const float*)d_in[8];
    const float* pw_b    = (const float*)d_in[9];
    const float* bn_g    = (const float*)d_in[10];
    const float* bn_b    = (const float*)d_in[11];
    const float* up_w    = (const float*)d_in[12];
    const float* up_b    = (const float*)d_in[13];
    const float* sdict   = (const float*)d_in[14];
    float* out = (float*)d_out;
    char* ws = (char*)d_ws;

    // layout (bytes)
    const size_t R1   = 33554432;   // spec16 -> enc[0]
    const size_t R2   = 33554432;   // enc[1]  (enc = r1, 67MB contiguous)
    const size_t ACT  = 16777216;   // f16 [b][t][c]
    char* r1   = ws;
    char* actA = ws + R1 + R2;
    char* actB = actA + ACT;
    char* wreg = actB + ACT;
    _Float16* W7   = (_Float16*)wreg;                      // 7*16384
    _Float16* Wd   = W7 + 7*16384;                         // 7*3*16384
    _Float16* Wp   = Wd + 7*3*16384;                       // 7*16384
    _Float16* Wup  = Wp + 7*16384;                         // 65536
    _Float16* Wfb  = Wup + 65536;                          // 65536
    float* stats   = (float*)(Wfb + 65536);                // 8*2*128 floats
    float* opart   = stats + 8*2*128;                      // 8*B*T floats (2 MB)
    const size_t TOTAL = R1 + R2 + 2*ACT
                       + (7*16384 + 7*3*16384 + 7*16384 + 65536 + 65536)*2
                       + 8*2*128*4 + (size_t)8*B_*T_*4;
    if (ws_size < TOTAL) {
        k_fill<<<(out_size+255)/256, 256, 0, stream>>>(out, 12345.0f);
        return;
    }
    _Float16* spec16 = (_Float16*)r1;
    _Float16* enc = (_Float16*)r1;            // [b][t][c], 67MB (spec16 dead after conv0)
    _Float16* At  = (_Float16*)(actA + 2097152);  // alias in actA (free after conv stack)

    // prep
    k_zero<<<(2048+255)/256, 256, 0, stream>>>(stats, 8*2*128);
    k_zero<<<(8*B_*T_+255)/256, 256, 0, stream>>>(opart, 8*B_*T_);
    k_pw7<<<(7*16384+255)/256, 256, 0, stream>>>(conv0_w, W7);
    k_pwd<<<(7*3*16384+255)/256, 256, 0, stream>>>(dil_w, Wd);
    k_cast<<<(7*16384+255)/256, 256, 0, stream>>>(pw_w, Wp, 7*16384);
    k_cast<<<(65536+255)/256, 256, 0, stream>>>(up_w, Wup, 65536);
    k_cast<<<(65536+255)/256, 256, 0, stream>>>(fb_w, Wfb, 65536);

    // front: MFMA filter bank, direct time-major f16
    k_fbm<<<dim3(T_/128, B_), 256, 0, stream>>>(x, Wfb, spec16);
    k_cv<7,false,false,true,false,true><<<dim3(T_/128,1,B_), 256, 0, stream>>>(
        spec16, W7, conv0_b, nullptr, nullptr, nullptr, nullptr, nullptr,
        stats + 0, (_Float16*)actA, 1, CH_);

    const int DILS[7] = {1, 3, 9, 27, 81, 243, 1};
    _Float16* cur = (_Float16*)actA;
    _Float16* nxt = (_Float16*)actB;
    for (int i = 0; i < 7; ++i) {
        const float* gi = (i == 0) ? bn0_g : bn_g + (i-1)*CH_;
        const float* bi = (i == 0) ? bn0_b : bn_b + (i-1)*CH_;
        k_cv<3,true,true,true,false,true><<<dim3(T_/128,1,B_), 256, 0, stream>>>(
            cur, Wd + (size_t)i*3*CH_*CH_, dil_b + i*CH_, Wp + (size_t)i*CH_*CH_,
            pw_b + i*CH_, stats + i*256, gi, bi, stats + (i+1)*256, nxt, DILS[i], CH_);
        _Float16* sw = cur; cur = nxt; nxt = sw;
    }
    // cur == actB; actA free -> At alias valid; r1/r2 free for enc (both batches)

    k_tr_at<<<dim3(ATOM_/32, EC_/32), dim3(32,8), 0, stream>>>(sdict, At);
    // up-projection + relu -> enc[b][t][c] f16 (both batches)
    k_cv<1,true,false,false,true,false><<<dim3(T_/128,EC_/128,B_), 256, 0, stream>>>(
        cur, Wup, up_b, nullptr, nullptr,
        stats + 7*256, bn_g + 6*CH_, bn_b + 6*CH_, nullptr, enc, 1, EC_);

    // dictionary conv: barrier-free enc-in-regs GEMM into per-c-chunk planes, then reduce
    k_gemm<<<dim3(T_/128, 8, B_*2), 256, 0, stream>>>(At, enc, opart);
    k_red<<<(B_*T_)/256, 256, 0, stream>>>(opart, out);
}

// Round 15
// 1211.061 us; speedup vs baseline: 3.1673x; 3.1673x over previous
//
#include <hip/hip_runtime.h>
#include <hip/hip_bf16.h>

#define B_ 2
#define T_ 32768
#define CH_ 128
#define EC_ 512
#define ATOM_ 2048
#define FBK_ 512

typedef __attribute__((ext_vector_type(8))) short s16x8;
typedef __attribute__((ext_vector_type(8))) _Float16 f16x8;
typedef __attribute__((ext_vector_type(4))) float f32x4;

__device__ __forceinline__ f16x8 ldh8(const _Float16* p) {
    union { s16x8 s; f16x8 h; } u; u.s = *(const s16x8*)p; return u.h;
}

__device__ __forceinline__ void gl_lds16(const _Float16* g, _Float16* l) {
    __builtin_amdgcn_global_load_lds(
        (const __attribute__((address_space(1))) unsigned int*)(g),
        (__attribute__((address_space(3))) unsigned int*)(l), 16, 0, 0);
}

// ---------------- MFMA filter bank: x[b,1,T] -> spec16[b][t][band] f16 ----------------
__global__ void __launch_bounds__(256) k_fbm(const float* __restrict__ x,
        const _Float16* __restrict__ Wfb, _Float16* __restrict__ spec16) {
    __shared__ _Float16 XA[128][72];
    __shared__ float xw[640];
    int tid = threadIdx.x;
    int lane = tid & 63;
    int wv = tid >> 6, wm = wv >> 1, wn = wv & 1;
    int ln15 = lane & 15, kh = lane >> 4;
    int t0 = blockIdx.x * 128;
    int b = blockIdx.y;

    for (int i = tid; i < 640; i += 256) {
        int g = t0 - 256 + i;
        xw[i] = (g >= 0 && g < T_) ? x[(size_t)b*T_ + g] : 0.f;
    }

    f32x4 acc[4][4];
    f32x4 zero = {0.f,0.f,0.f,0.f};
#pragma unroll
    for (int m = 0; m < 4; ++m)
#pragma unroll
        for (int n = 0; n < 4; ++n) acc[m][n] = zero;

    for (int c = 0; c < 8; ++c) {
        int k0 = c*64;
        __syncthreads();               // xw ready on c==0; XA WAR on c>0
#pragma unroll
        for (int q = 0; q < 4; ++q) {
            int idx = tid + q*256;
            int r = idx >> 3, ko = idx & 7;
            int base = r + k0 + ko*8;
            f16x8 v;
#pragma unroll
            for (int j = 0; j < 8; ++j) v[j] = (_Float16)xw[base + j];
            union { f16x8 h; s16x8 s; } u; u.h = v;
            *(s16x8*)&XA[r][ko*8] = u.s;
        }
        __syncthreads();
#pragma unroll
        for (int kt = 0; kt < 2; ++kt) {
            f16x8 af[4], bf[4];
#pragma unroll
            for (int m = 0; m < 4; ++m) af[m] = ldh8(&XA[wm*64+m*16+ln15][kt*32+kh*8]);
#pragma unroll
            for (int n = 0; n < 4; ++n)
                bf[n] = ldh8(Wfb + (size_t)(wn*64+n*16+ln15)*FBK_ + k0 + kt*32 + kh*8);
#pragma unroll
            for (int m = 0; m < 4; ++m)
#pragma unroll
                for (int n = 0; n < 4; ++n)
                    acc[m][n] = __builtin_amdgcn_mfma_f32_16x16x32_f16(af[m], bf[n], acc[m][n], 0,0,0);
        }
    }
#pragma unroll
    for (int mf = 0; mf < 4; ++mf)
#pragma unroll
        for (int nf = 0; nf < 4; ++nf) {
            int band = wn*64 + nf*16 + ln15;
#pragma unroll
            for (int j = 0; j < 4; ++j) {
                int tl = wm*64 + mf*16 + kh*4 + j;
                spec16[((size_t)b*T_ + t0 + tl)*CH_ + band] = (_Float16)acc[mf][nf][j];
            }
        }
}

// ---------------- weight prep ----------------
__global__ void k_pw7(const float* __restrict__ w, _Float16* __restrict__ W7) {
    int i = blockIdx.x*256+threadIdx.x;
    if (i >= 7*16384) return;
    int k = i / 16384, r = i % 16384; int co = r >> 7, ci = r & 127;
    W7[i] = (_Float16)w[(co*CH_+ci)*7 + k];
}
__global__ void k_pwd(const float* __restrict__ w, _Float16* __restrict__ Wd) {
    int i = blockIdx.x*256+threadIdx.x;
    if (i >= 7*3*16384) return;
    int st = i / 49152, r = i % 49152; int k = r / 16384, r2 = r % 16384;
    int co = r2 >> 7, ci = r2 & 127;
    Wd[i] = (_Float16)w[((size_t)(st*CH_+co)*CH_+ci)*3 + k];
}
__global__ void k_cast(const float* __restrict__ in, _Float16* __restrict__ out, int n) {
    int i = blockIdx.x*256+threadIdx.x;
    if (i < n) out[i] = (_Float16)in[i];
}
__global__ void k_zero(float* __restrict__ p, int n) {
    int i = blockIdx.x*256+threadIdx.x;
    if (i < n) p[i] = 0.f;
}

// ---------------- fused MFMA conv block, 64-row t-tile (4 blocks/CU) ----------------
// waves: wm = t 32-half, wn = co 64-half. acc[2][4].
template<int NTAP, bool NORM, bool PW, bool LRELU, bool RELU, bool STATS>
__global__ void __launch_bounds__(256) k_cv(
        const _Float16* __restrict__ in, const _Float16* __restrict__ W,
        const float* __restrict__ bias, const _Float16* __restrict__ Wp_,
        const float* __restrict__ pbias, const float* __restrict__ stats_in,
        const float* __restrict__ g, const float* __restrict__ bb,
        float* __restrict__ stats_out, _Float16* __restrict__ outp,
        int dil, int ostride) {
    __shared__ _Float16 XT[64][136];
    __shared__ _Float16 Y1[PW?64:1][PW?136:1];
    __shared__ float AffA[NORM?128:1], AffB[NORM?128:1];

    int tid = threadIdx.x;
    int lane = tid & 63;
    int wv = tid >> 6, wm = wv >> 1, wn = wv & 1;
    int ln15 = lane & 15, kh = lane >> 4;
    int t0 = blockIdx.x * 64;
    int nch = blockIdx.y;
    int b = blockIdx.z;
    int ncol0 = nch * 128;
    const _Float16* inb = in + (size_t)b*T_*CH_;
    const _Float16* W_eff = W + (size_t)ncol0*CH_;
    const float* bias_eff = bias + ncol0;

    if (NORM) {
        if (tid < 128) {
            const float invN = 1.f/(float)(B_*T_);
            float s1 = stats_in[tid], s2 = stats_in[128+tid];
            float m = s1*invN, var = s2*invN - m*m;
            float A = rsqrtf(var + 1e-5f) * g[tid];
            AffA[tid] = A; AffB[tid] = bb[tid] - m*A;
        }
    }

    f32x4 acc[2][4];
    f32x4 zero = {0.f,0.f,0.f,0.f};
#pragma unroll
    for (int m = 0; m < 2; ++m)
#pragma unroll
        for (int n = 0; n < 4; ++n) acc[m][n] = zero;

    for (int tap = 0; tap < NTAP; ++tap) {
        int tp = tap;
        if (PW) tp = (tap==0) ? 0 : ((tap==1) ? 2 : 1);   // center tap LAST (kept for residual)
        int off = (tp - NTAP/2)*dil;
        const _Float16* Wt = W_eff + (size_t)tp*CH_*CH_;
        __syncthreads();               // AffA ready (tap0) / XT WAR (tap>0)
#pragma unroll
        for (int q = 0; q < 4; ++q) {
            int idx = tid + q*256;
            int lt = idx >> 4, ck = idx & 15;
            int gt = t0 + lt + off;
            s16x8 v = {0,0,0,0,0,0,0,0};
            bool valid = (gt >= 0 && gt < T_);
            if (valid) {
                v = *(const s16x8*)(inb + (size_t)gt*CH_ + ck*8);
                if (NORM) {
                    union {s16x8 s; f16x8 h;} u; u.s = v;
                    f16x8 r;
#pragma unroll
                    for (int j = 0; j < 8; ++j) {
                        float f = (float)u.h[j];
                        f = fmaf(f, AffA[ck*8+j], AffB[ck*8+j]);
                        r[j] = (_Float16)f;
                    }
                    union {f16x8 h; s16x8 s;} w2; w2.h = r; v = w2.s;
                }
            }
            *(s16x8*)&XT[lt][ck*8] = v;
        }
        __syncthreads();
#pragma unroll
        for (int kt = 0; kt < 4; ++kt) {
            f16x8 af[2], bf[4];
#pragma unroll
            for (int m = 0; m < 2; ++m) af[m] = ldh8(&XT[wm*32+m*16+ln15][kt*32+kh*8]);
#pragma unroll
            for (int n = 0; n < 4; ++n)
                bf[n] = ldh8(Wt + (size_t)(wn*64+n*16+ln15)*CH_ + kt*32 + kh*8);
#pragma unroll
            for (int m = 0; m < 2; ++m)
#pragma unroll
                for (int n = 0; n < 4; ++n)
                    acc[m][n] = __builtin_amdgcn_mfma_f32_16x16x32_f16(af[m], bf[n], acc[m][n], 0,0,0);
        }
    }

    if (PW) {
#pragma unroll
        for (int mf = 0; mf < 2; ++mf)
#pragma unroll
            for (int nf = 0; nf < 4; ++nf) {
                int co = wn*64 + nf*16 + ln15;
                float bv = bias_eff[co];
#pragma unroll
                for (int j = 0; j < 4; ++j) {
                    int tl = wm*32 + mf*16 + kh*4 + j;
                    Y1[tl][co] = (_Float16)(acc[mf][nf][j] + bv);
                }
            }
#pragma unroll
        for (int m = 0; m < 2; ++m)
#pragma unroll
            for (int n = 0; n < 4; ++n) acc[m][n] = zero;
        __syncthreads();
#pragma unroll
        for (int kt = 0; kt < 4; ++kt) {
            f16x8 af[2], bf[4];
#pragma unroll
            for (int m = 0; m < 2; ++m) af[m] = ldh8(&Y1[wm*32+m*16+ln15][kt*32+kh*8]);
#pragma unroll
            for (int n = 0; n < 4; ++n)
                bf[n] = ldh8(Wp_ + (size_t)(wn*64+n*16+ln15)*CH_ + kt*32 + kh*8);
#pragma unroll
            for (int m = 0; m < 2; ++m)
#pragma unroll
                for (int n = 0; n < 4; ++n)
                    acc[m][n] = __builtin_amdgcn_mfma_f32_16x16x32_f16(af[m], bf[n], acc[m][n], 0,0,0);
        }
    }

#pragma unroll
    for (int nf = 0; nf < 4; ++nf) {
        int co = wn*64 + nf*16 + ln15;
        float bfin = PW ? pbias[co] : bias_eff[co];
        float s = 0.f, s2 = 0.f;
#pragma unroll
        for (int mf = 0; mf < 2; ++mf) {
#pragma unroll
            for (int j = 0; j < 4; ++j) {
                int tl = wm*32 + mf*16 + kh*4 + j;
                float v = acc[mf][nf][j] + bfin;
                if (PW) v += (float)XT[tl][co];    // residual = normalized center tile
                if (LRELU) v = v >= 0.f ? v : 0.2f*v;
                if (RELU)  v = fmaxf(v, 0.f);
                outp[((size_t)b*T_ + t0 + tl)*ostride + ncol0 + co] = (_Float16)v;
                if (STATS) { s += v; s2 += v*v; }
            }
        }
        if (STATS) {
            s  += __shfl_down(s, 16);  s  += __shfl_down(s, 32);
            s2 += __shfl_down(s2, 16); s2 += __shfl_down(s2, 32);
            if (kh == 0) {
                atomicAdd(&stats_out[co], s);
                atomicAdd(&stats_out[128+co], s2);
            }
        }
    }
}

// ---------------- transpose static_dict [512][2048] fp32 -> At [2048][512] f16 ----------------
__global__ void k_tr_at(const float* __restrict__ sd, _Float16* __restrict__ At) {
    __shared__ float tile[32][33];
    int tau0 = blockIdx.x*32;
    int c0 = blockIdx.y*32;
    int tx = threadIdx.x, ty = threadIdx.y;
#pragma unroll
    for (int j = 0; j < 4; ++j)
        tile[ty+j*8][tx] = sd[(size_t)(c0+ty+j*8)*ATOM_ + tau0 + tx];
    __syncthreads();
#pragma unroll
    for (int j = 0; j < 4; ++j)
        At[(size_t)(tau0+ty+j*8)*EC_ + c0 + tx] = (_Float16)tile[tx][ty+j*8];
}

// ---------------- GEMM: T3 minimum 2-phase dbuf (r12-verified) + fused anti-diag ----------
__global__ void __launch_bounds__(256) k_gemm(const _Float16* __restrict__ At,
                                              const _Float16* __restrict__ enc,
                                              float* __restrict__ out) {
    __shared__ _Float16 lA[2][128*64];  // gl_lds dest (linear); source pre-swizzled
    __shared__ _Float16 lB[2][128*64];
    __shared__ float pt[256];
    int tid = threadIdx.x;
    int lane = tid & 63;
    int wv = tid >> 6;
    int wm = wv >> 1, wn = wv & 1;
    int id = blockIdx.x;
    int sOuter = id >> 6;
    int inner  = id & 63;
    int tT = inner >> 2;
    int sT = sOuter*4 + (inner & 3);
    int b  = blockIdx.y;
    const _Float16* Ab = At + (size_t)tT*128*EC_;
    const _Float16* Eb = enc + ((size_t)b*T_ + (size_t)sT*128)*EC_;
    int ln15 = lane & 15, kh = lane >> 4;
    int lrow = lane >> 3;
    int scol = (((lane & 7) ^ lrow)) * 8;
    pt[tid] = 0.f;
    f32x4 acc[4][4];
    f32x4 zero = {0.f,0.f,0.f,0.f};
#pragma unroll
    for (int m = 0; m < 4; ++m)
#pragma unroll
        for (int n = 0; n < 4; ++n) acc[m][n] = zero;

#pragma unroll
    for (int c = 0; c < 4; ++c) {
        int brow = wv*32 + c*8;
        gl_lds16(Ab + (size_t)(brow + lrow)*EC_ + scol, &lA[0][brow*64]);
        gl_lds16(Eb + (size_t)(brow + lrow)*EC_ + scol, &lB[0][brow*64]);
    }
    asm volatile("s_waitcnt vmcnt(0)" ::: "memory");
    __builtin_amdgcn_s_barrier();
    __builtin_amdgcn_sched_barrier(0);

    int cur = 0;
    for (int kt = 0; kt < 8; ++kt) {
        if (kt < 7) {
            int k0 = (kt+1)*64;
#pragma unroll
            for (int c = 0; c < 4; ++c) {
                int brow = wv*32 + c*8;
                gl_lds16(Ab + (size_t)(brow + lrow)*EC_ + k0 + scol, &lA[cur^1][brow*64]);
                gl_lds16(Eb + (size_t)(brow + lrow)*EC_ + k0 + scol, &lB[cur^1][brow*64]);
            }
        }
#pragma unroll
        for (int kk = 0; kk < 2; ++kk) {
            f16x8 af[4], bfr[4];
#pragma unroll
            for (int m = 0; m < 4; ++m) {
                int r = wm*64 + m*16 + ln15;
                af[m] = ldh8(&lA[cur][r*64 + (((kk<<2)|kh) ^ (r & 7))*8]);
            }
#pragma unroll
            for (int n = 0; n < 4; ++n) {
                int r = wn*64 + n*16 + ln15;
                bfr[n] = ldh8(&lB[cur][r*64 + (((kk<<2)|kh) ^ (r & 7))*8]);
            }
#pragma unroll
            for (int m = 0; m < 4; ++m)
#pragma unroll
                for (int n = 0; n < 4; ++n)
                    acc[m][n] = __builtin_amdgcn_mfma_f32_16x16x32_f16(af[m], bfr[n], acc[m][n], 0, 0, 0);
        }
        asm volatile("s_waitcnt lgkmcnt(0)" ::: "memory");
        if (kt < 7) asm volatile("s_waitcnt vmcnt(0)" ::: "memory");
        __builtin_amdgcn_s_barrier();
        __builtin_amdgcn_sched_barrier(0);
        cur ^= 1;
    }

#pragma unroll
    for (int mn = 0; mn <= 6; ++mn) {
#pragma unroll
        for (int j = 0; j < 4; ++j) {
            float v = 0.f;
#pragma unroll
            for (int m = 0; m < 4; ++m) {
                int n = mn - m;
                if (n >= 0 && n < 4) v += acc[m][n][j];
            }
            int tl = (wm + wn)*64 + mn*16 + kh*4 + j + ln15;
            unsafeAtomicAdd(&pt[tl], v);
        }
    }
    __syncthreads();
    if (tid < 255) {
        int tg = tT*128 + sT*128 + tid;
        if (tg < T_) unsafeAtomicAdd(&out[(size_t)b*T_ + tg], pt[tid]);
    }
}

__global__ void k_fill(float* __restrict__ out, float val) {
    out[blockIdx.x*256 + threadIdx.x] = val;
}

extern "C" void kernel_launch(void* const* d_in, const int* in_sizes, int n_in,
                              void* d_out, int out_size, void* d_ws, size_t ws_size,
                              hipStream_t stream) {
    const float* x       = (const float*)d_in[0];
    const float* fb_w    = (const float*)d_in[1];
    const float* conv0_w = (const float*)d_in[2];
    const float* conv0_b = (const float*)d_in[3];
    const float* bn0_g   = (const float*)d_in[4];
    const float* bn0_b   = (const float*)d_in[5];
    const float* dil_w   = (const float*)d_in[6];
    const float* dil_b   = (const float*)d_in[7];
    const float* pw_w    = (const float*)d_in[8];
    const float* pw_b    = (const float*)d_in[9];
    const float* bn_g    = (const float*)d_in[10];
    const float* bn_b    = (const float*)d_in[11];
    const float* up_w    = (const float*)d_in[12];
    const float* up_b    = (const float*)d_in[13];
    const float* sdict   = (const float*)d_in[14];
    float* out = (float*)d_out;
    char* ws = (char*)d_ws;

    // layout (bytes)
    const size_t R1   = 33554432;   // spec16 -> enc[0]
    const size_t R2   = 33554432;   // enc[1]  (enc = r1, 67MB contiguous)
    const size_t ACT  = 16777216;   // f16 [b][t][c]
    char* r1   = ws;
    char* actA = ws + R1 + R2;
    char* actB = actA + ACT;
    char* wreg = actB + ACT;
    _Float16* W7   = (_Float16*)wreg;                      // 7*16384
    _Float16* Wd   = W7 + 7*16384;                         // 7*3*16384
    _Float16* Wp   = Wd + 7*3*16384;                       // 7*16384
    _Float16* Wup  = Wp + 7*16384;                         // 65536
    _Float16* Wfb  = Wup + 65536;                          // 65536
    float* stats   = (float*)(Wfb + 65536);                // 8*2*128 floats
    const size_t TOTAL = R1 + R2 + 2*ACT
                       + (7*16384 + 7*3*16384 + 7*16384 + 65536 + 65536)*2 + 8*2*128*4;
    if (ws_size < TOTAL) {
        k_fill<<<(out_size+255)/256, 256, 0, stream>>>(out, 12345.0f);
        return;
    }
    _Float16* spec16 = (_Float16*)r1;
    _Float16* enc = (_Float16*)r1;            // [b][t][c], 67MB (spec16 dead after conv0)
    _Float16* At  = (_Float16*)(actA + 2097152);  // alias in actA (free after conv stack)

    // prep
    k_zero<<<(2048+255)/256, 256, 0, stream>>>(stats, 8*2*128);
    k_pw7<<<(7*16384+255)/256, 256, 0, stream>>>(conv0_w, W7);
    k_pwd<<<(7*3*16384+255)/256, 256, 0, stream>>>(dil_w, Wd);
    k_cast<<<(7*16384+255)/256, 256, 0, stream>>>(pw_w, Wp, 7*16384);
    k_cast<<<(65536+255)/256, 256, 0, stream>>>(up_w, Wup, 65536);
    k_cast<<<(65536+255)/256, 256, 0, stream>>>(fb_w, Wfb, 65536);

    // front: MFMA filter bank, direct time-major f16
    k_fbm<<<dim3(T_/128, B_), 256, 0, stream>>>(x, Wfb, spec16);
    k_cv<7,false,false,true,false,true><<<dim3(T_/64,1,B_), 256, 0, stream>>>(
        spec16, W7, conv0_b, nullptr, nullptr, nullptr, nullptr, nullptr,
        stats + 0, (_Float16*)actA, 1, CH_);

    const int DILS[7] = {1, 3, 9, 27, 81, 243, 1};
    _Float16* cur = (_Float16*)actA;
    _Float16* nxt = (_Float16*)actB;
    for (int i = 0; i < 7; ++i) {
        const float* gi = (i == 0) ? bn0_g : bn_g + (i-1)*CH_;
        const float* bi = (i == 0) ? bn0_b : bn_b + (i-1)*CH_;
        k_cv<3,true,true,true,false,true><<<dim3(T_/64,1,B_), 256, 0, stream>>>(
            cur, Wd + (size_t)i*3*CH_*CH_, dil_b + i*CH_, Wp + (size_t)i*CH_*CH_,
            pw_b + i*CH_, stats + i*256, gi, bi, stats + (i+1)*256, nxt, DILS[i], CH_);
        _Float16* sw = cur; cur = nxt; nxt = sw;
    }
    // cur == actB; actA free -> At alias valid; r1/r2 free for enc (both batches)

    k_tr_at<<<dim3(ATOM_/32, EC_/32), dim3(32,8), 0, stream>>>(sdict, At);
    // up-projection + relu -> enc[b][t][c] f16 (both batches)
    k_cv<1,true,false,false,true,false><<<dim3(T_/64,EC_/128,B_), 256, 0, stream>>>(
        cur, Wup, up_b, nullptr, nullptr,
        stats + 7*256, bn_g + 6*CH_, bn_b + 6*CH_, nullptr, enc, 1, EC_);

    // dictionary conv: zero out, then dbuf GEMM with fused anti-diagonal atomics
    k_zero<<<(B_*T_+255)/256, 256, 0, stream>>>(out, B_*T_);
    k_gemm<<<dim3(4096, B_), 256, 0, stream>>>(At, enc, out);
}

// Round 16
// 941.223 us; speedup vs baseline: 4.0753x; 1.2867x over previous
//
#include <hip/hip_runtime.h>
#include <hip/hip_bf16.h>

#define B_ 2
#define T_ 32768
#define CH_ 128
#define EC_ 512
#define ATOM_ 2048
#define FBK_ 512

typedef __attribute__((ext_vector_type(8))) short s16x8;
typedef __attribute__((ext_vector_type(8))) _Float16 f16x8;
typedef __attribute__((ext_vector_type(4))) float f32x4;

__device__ __forceinline__ f16x8 ldh8(const _Float16* p) {
    union { s16x8 s; f16x8 h; } u; u.s = *(const s16x8*)p; return u.h;
}

__device__ __forceinline__ void gl_lds16(const _Float16* g, _Float16* l) {
    __builtin_amdgcn_global_load_lds(
        (const __attribute__((address_space(1))) unsigned int*)(g),
        (__attribute__((address_space(3))) unsigned int*)(l), 16, 0, 0);
}

// ---------------- MFMA filter bank: x[b,1,T] -> spec16[b][t][band] f16 ----------------
__global__ void __launch_bounds__(256) k_fbm(const float* __restrict__ x,
        const _Float16* __restrict__ Wfb, _Float16* __restrict__ spec16) {
    __shared__ _Float16 XA[128][72];
    __shared__ float xw[640];
    int tid = threadIdx.x;
    int lane = tid & 63;
    int wv = tid >> 6, wm = wv >> 1, wn = wv & 1;
    int ln15 = lane & 15, kh = lane >> 4;
    int t0 = blockIdx.x * 128;
    int b = blockIdx.y;

    for (int i = tid; i < 640; i += 256) {
        int g = t0 - 256 + i;
        xw[i] = (g >= 0 && g < T_) ? x[(size_t)b*T_ + g] : 0.f;
    }

    f32x4 acc[4][4];
    f32x4 zero = {0.f,0.f,0.f,0.f};
#pragma unroll
    for (int m = 0; m < 4; ++m)
#pragma unroll
        for (int n = 0; n < 4; ++n) acc[m][n] = zero;

    for (int c = 0; c < 8; ++c) {
        int k0 = c*64;
        __syncthreads();               // xw ready on c==0; XA WAR on c>0
#pragma unroll
        for (int q = 0; q < 4; ++q) {
            int idx = tid + q*256;
            int r = idx >> 3, ko = idx & 7;
            int base = r + k0 + ko*8;
            f16x8 v;
#pragma unroll
            for (int j = 0; j < 8; ++j) v[j] = (_Float16)xw[base + j];
            union { f16x8 h; s16x8 s; } u; u.h = v;
            *(s16x8*)&XA[r][ko*8] = u.s;
        }
        __syncthreads();
#pragma unroll
        for (int kt = 0; kt < 2; ++kt) {
            f16x8 af[4], bf[4];
#pragma unroll
            for (int m = 0; m < 4; ++m) af[m] = ldh8(&XA[wm*64+m*16+ln15][kt*32+kh*8]);
#pragma unroll
            for (int n = 0; n < 4; ++n)
                bf[n] = ldh8(Wfb + (size_t)(wn*64+n*16+ln15)*FBK_ + k0 + kt*32 + kh*8);
#pragma unroll
            for (int m = 0; m < 4; ++m)
#pragma unroll
                for (int n = 0; n < 4; ++n)
                    acc[m][n] = __builtin_amdgcn_mfma_f32_16x16x32_f16(af[m], bf[n], acc[m][n], 0,0,0);
        }
    }
#pragma unroll
    for (int mf = 0; mf < 4; ++mf)
#pragma unroll
        for (int nf = 0; nf < 4; ++nf) {
            int band = wn*64 + nf*16 + ln15;
#pragma unroll
            for (int j = 0; j < 4; ++j) {
                int tl = wm*64 + mf*16 + kh*4 + j;
                spec16[((size_t)b*T_ + t0 + tl)*CH_ + band] = (_Float16)acc[mf][nf][j];
            }
        }
}

// ---------------- weight prep ----------------
__global__ void k_pw7(const float* __restrict__ w, _Float16* __restrict__ W7) {
    int i = blockIdx.x*256+threadIdx.x;
    if (i >= 7*16384) return;
    int k = i / 16384, r = i % 16384; int co = r >> 7, ci = r & 127;
    W7[i] = (_Float16)w[(co*CH_+ci)*7 + k];
}
__global__ void k_pwd(const float* __restrict__ w, _Float16* __restrict__ Wd) {
    int i = blockIdx.x*256+threadIdx.x;
    if (i >= 7*3*16384) return;
    int st = i / 49152, r = i % 49152; int k = r / 16384, r2 = r % 16384;
    int co = r2 >> 7, ci = r2 & 127;
    Wd[i] = (_Float16)w[((size_t)(st*CH_+co)*CH_+ci)*3 + k];
}
__global__ void k_cast(const float* __restrict__ in, _Float16* __restrict__ out, int n) {
    int i = blockIdx.x*256+threadIdx.x;
    if (i < n) out[i] = (_Float16)in[i];
}
__global__ void k_zero(float* __restrict__ p, int n) {
    int i = blockIdx.x*256+threadIdx.x;
    if (i < n) p[i] = 0.f;
}

// ---------------- fused MFMA conv block, 128-row t-tile (r12-verified) ----------------
template<int NTAP, bool NORM, bool PW, bool LRELU, bool RELU, bool STATS>
__global__ void __launch_bounds__(256) k_cv(
        const _Float16* __restrict__ in, const _Float16* __restrict__ W,
        const float* __restrict__ bias, const _Float16* __restrict__ Wp_,
        const float* __restrict__ pbias, const float* __restrict__ stats_in,
        const float* __restrict__ g, const float* __restrict__ bb,
        float* __restrict__ stats_out, _Float16* __restrict__ outp,
        int dil, int ostride) {
    __shared__ _Float16 XT[128][136];
    __shared__ _Float16 Y1[PW?128:1][PW?136:1];
    __shared__ float AffA[NORM?128:1], AffB[NORM?128:1];

    int tid = threadIdx.x;
    int lane = tid & 63;
    int wv = tid >> 6, wm = wv >> 1, wn = wv & 1;
    int ln15 = lane & 15, kh = lane >> 4;
    int t0 = blockIdx.x * 128;
    int nch = blockIdx.y;
    int b = blockIdx.z;
    int ncol0 = nch * 128;
    const _Float16* inb = in + (size_t)b*T_*CH_;
    const _Float16* W_eff = W + (size_t)ncol0*CH_;
    const float* bias_eff = bias + ncol0;

    if (NORM) {
        if (tid < 128) {
            const float invN = 1.f/(float)(B_*T_);
            float s1 = stats_in[tid], s2 = stats_in[128+tid];
            float m = s1*invN, var = s2*invN - m*m;
            float A = rsqrtf(var + 1e-5f) * g[tid];
            AffA[tid] = A; AffB[tid] = bb[tid] - m*A;
        }
    }

    f32x4 acc[4][4];
    f32x4 zero = {0.f,0.f,0.f,0.f};
#pragma unroll
    for (int m = 0; m < 4; ++m)
#pragma unroll
        for (int n = 0; n < 4; ++n) acc[m][n] = zero;

    for (int tap = 0; tap < NTAP; ++tap) {
        int tp = tap;
        if (PW) tp = (tap==0) ? 0 : ((tap==1) ? 2 : 1);   // center tap LAST (kept for residual)
        int off = (tp - NTAP/2)*dil;
        const _Float16* Wt = W_eff + (size_t)tp*CH_*CH_;
        __syncthreads();               // AffA ready (tap0) / XT WAR (tap>0)
#pragma unroll
        for (int q = 0; q < 8; ++q) {
            int idx = tid + q*256;
            int lt = idx >> 4, ck = idx & 15;
            int gt = t0 + lt + off;
            s16x8 v = {0,0,0,0,0,0,0,0};
            bool valid = (gt >= 0 && gt < T_);
            if (valid) {
                v = *(const s16x8*)(inb + (size_t)gt*CH_ + ck*8);
                if (NORM) {
                    union {s16x8 s; f16x8 h;} u; u.s = v;
                    f16x8 r;
#pragma unroll
                    for (int j = 0; j < 8; ++j) {
                        float f = (float)u.h[j];
                        f = fmaf(f, AffA[ck*8+j], AffB[ck*8+j]);
                        r[j] = (_Float16)f;
                    }
                    union {f16x8 h; s16x8 s;} w2; w2.h = r; v = w2.s;
                }
            }
            *(s16x8*)&XT[lt][ck*8] = v;
        }
        __syncthreads();
#pragma unroll
        for (int kt = 0; kt < 4; ++kt) {
            f16x8 af[4], bf[4];
#pragma unroll
            for (int m = 0; m < 4; ++m) af[m] = ldh8(&XT[wm*64+m*16+ln15][kt*32+kh*8]);
#pragma unroll
            for (int n = 0; n < 4; ++n)
                bf[n] = ldh8(Wt + (size_t)(wn*64+n*16+ln15)*CH_ + kt*32 + kh*8);
#pragma unroll
            for (int m = 0; m < 4; ++m)
#pragma unroll
                for (int n = 0; n < 4; ++n)
                    acc[m][n] = __builtin_amdgcn_mfma_f32_16x16x32_f16(af[m], bf[n], acc[m][n], 0,0,0);
        }
    }

    if (PW) {
#pragma unroll
        for (int mf = 0; mf < 4; ++mf)
#pragma unroll
            for (int nf = 0; nf < 4; ++nf) {
                int co = wn*64 + nf*16 + ln15;
                float bv = bias_eff[co];
#pragma unroll
                for (int j = 0; j < 4; ++j) {
                    int tl = wm*64 + mf*16 + kh*4 + j;
                    Y1[tl][co] = (_Float16)(acc[mf][nf][j] + bv);
                }
            }
#pragma unroll
        for (int m = 0; m < 4; ++m)
#pragma unroll
            for (int n = 0; n < 4; ++n) acc[m][n] = zero;
        __syncthreads();
#pragma unroll
        for (int kt = 0; kt < 4; ++kt) {
            f16x8 af[4], bf[4];
#pragma unroll
            for (int m = 0; m < 4; ++m) af[m] = ldh8(&Y1[wm*64+m*16+ln15][kt*32+kh*8]);
#pragma unroll
            for (int n = 0; n < 4; ++n)
                bf[n] = ldh8(Wp_ + (size_t)(wn*64+n*16+ln15)*CH_ + kt*32 + kh*8);
#pragma unroll
            for (int m = 0; m < 4; ++m)
#pragma unroll
                for (int n = 0; n < 4; ++n)
                    acc[m][n] = __builtin_amdgcn_mfma_f32_16x16x32_f16(af[m], bf[n], acc[m][n], 0,0,0);
        }
    }

#pragma unroll
    for (int nf = 0; nf < 4; ++nf) {
        int co = wn*64 + nf*16 + ln15;
        float bfin = PW ? pbias[co] : bias_eff[co];
        float s = 0.f, s2 = 0.f;
#pragma unroll
        for (int mf = 0; mf < 4; ++mf) {
#pragma unroll
            for (int j = 0; j < 4; ++j) {
                int tl = wm*64 + mf*16 + kh*4 + j;
                float v = acc[mf][nf][j] + bfin;
                if (PW) v += (float)XT[tl][co];    // residual = normalized center tile
                if (LRELU) v = v >= 0.f ? v : 0.2f*v;
                if (RELU)  v = fmaxf(v, 0.f);
                outp[((size_t)b*T_ + t0 + tl)*ostride + ncol0 + co] = (_Float16)v;
                if (STATS) { s += v; s2 += v*v; }
            }
        }
        if (STATS) {
            s  += __shfl_down(s, 16);  s  += __shfl_down(s, 32);
            s2 += __shfl_down(s2, 16); s2 += __shfl_down(s2, 32);
            if (kh == 0) {
                atomicAdd(&stats_out[co], s);
                atomicAdd(&stats_out[128+co], s2);
            }
        }
    }
}

// ---------------- transpose static_dict [512][2048] fp32 -> At [2048][512] f16 ----------------
__global__ void k_tr_at(const float* __restrict__ sd, _Float16* __restrict__ At) {
    __shared__ float tile[32][33];
    int tau0 = blockIdx.x*32;
    int c0 = blockIdx.y*32;
    int tx = threadIdx.x, ty = threadIdx.y;
#pragma unroll
    for (int j = 0; j < 4; ++j)
        tile[ty+j*8][tx] = sd[(size_t)(c0+ty+j*8)*ATOM_ + tau0 + tx];
    __syncthreads();
#pragma unroll
    for (int j = 0; j < 4; ++j)
        At[(size_t)(tau0+ty+j*8)*EC_ + c0 + tx] = (_Float16)tile[tx][ty+j*8];
}

// ---------------- GEMM: r12 dbuf + XCD-chunked block swizzle (T1) ----------------
__global__ void __launch_bounds__(256) k_gemm(const _Float16* __restrict__ At,
                                              const _Float16* __restrict__ enc,
                                              float* __restrict__ out) {
    __shared__ _Float16 lA[2][128*64];  // gl_lds dest (linear); source pre-swizzled
    __shared__ _Float16 lB[2][128*64];
    __shared__ float pt[256];
    int tid = threadIdx.x;
    int lane = tid & 63;
    int wv = tid >> 6;
    int wm = wv >> 1, wn = wv & 1;
    // XCD swizzle: raw%8 = XCD -> give each XCD a contiguous 512-id chunk (bijective, 4096%8==0)
    int raw = blockIdx.x;
    int id = (raw & 7) * 512 + (raw >> 3);
    // decode: 64-id window = 4 sT x 16 tT -> enc slice 512KB + At 2MB stay L2-hot per XCD
    int sOuter = id >> 6;
    int inner  = id & 63;
    int tT = inner >> 2;
    int sT = sOuter*4 + (inner & 3);
    int b  = blockIdx.y;
    const _Float16* Ab = At + (size_t)tT*128*EC_;
    const _Float16* Eb = enc + ((size_t)b*T_ + (size_t)sT*128)*EC_;
    int ln15 = lane & 15, kh = lane >> 4;
    int lrow = lane >> 3;
    int scol = (((lane & 7) ^ lrow)) * 8;
    pt[tid] = 0.f;
    f32x4 acc[4][4];
    f32x4 zero = {0.f,0.f,0.f,0.f};
#pragma unroll
    for (int m = 0; m < 4; ++m)
#pragma unroll
        for (int n = 0; n < 4; ++n) acc[m][n] = zero;

#pragma unroll
    for (int c = 0; c < 4; ++c) {
        int brow = wv*32 + c*8;
        gl_lds16(Ab + (size_t)(brow + lrow)*EC_ + scol, &lA[0][brow*64]);
        gl_lds16(Eb + (size_t)(brow + lrow)*EC_ + scol, &lB[0][brow*64]);
    }
    asm volatile("s_waitcnt vmcnt(0)" ::: "memory");
    __builtin_amdgcn_s_barrier();
    __builtin_amdgcn_sched_barrier(0);

    int cur = 0;
    for (int kt = 0; kt < 8; ++kt) {
        if (kt < 7) {
            int k0 = (kt+1)*64;
#pragma unroll
            for (int c = 0; c < 4; ++c) {
                int brow = wv*32 + c*8;
                gl_lds16(Ab + (size_t)(brow + lrow)*EC_ + k0 + scol, &lA[cur^1][brow*64]);
                gl_lds16(Eb + (size_t)(brow + lrow)*EC_ + k0 + scol, &lB[cur^1][brow*64]);
            }
        }
#pragma unroll
        for (int kk = 0; kk < 2; ++kk) {
            f16x8 af[4], bfr[4];
#pragma unroll
            for (int m = 0; m < 4; ++m) {
                int r = wm*64 + m*16 + ln15;
                af[m] = ldh8(&lA[cur][r*64 + (((kk<<2)|kh) ^ (r & 7))*8]);
            }
#pragma unroll
            for (int n = 0; n < 4; ++n) {
                int r = wn*64 + n*16 + ln15;
                bfr[n] = ldh8(&lB[cur][r*64 + (((kk<<2)|kh) ^ (r & 7))*8]);
            }
#pragma unroll
            for (int m = 0; m < 4; ++m)
#pragma unroll
                for (int n = 0; n < 4; ++n)
                    acc[m][n] = __builtin_amdgcn_mfma_f32_16x16x32_f16(af[m], bfr[n], acc[m][n], 0, 0, 0);
        }
        asm volatile("s_waitcnt lgkmcnt(0)" ::: "memory");
        if (kt < 7) asm volatile("s_waitcnt vmcnt(0)" ::: "memory");
        __builtin_amdgcn_s_barrier();
        __builtin_amdgcn_sched_barrier(0);
        cur ^= 1;
    }

#pragma unroll
    for (int mn = 0; mn <= 6; ++mn) {
#pragma unroll
        for (int j = 0; j < 4; ++j) {
            float v = 0.f;
#pragma unroll
            for (int m = 0; m < 4; ++m) {
                int n = mn - m;
                if (n >= 0 && n < 4) v += acc[m][n][j];
            }
            int tl = (wm + wn)*64 + mn*16 + kh*4 + j + ln15;
            unsafeAtomicAdd(&pt[tl], v);
        }
    }
    __syncthreads();
    if (tid < 255) {
        int tg = tT*128 + sT*128 + tid;
        if (tg < T_) unsafeAtomicAdd(&out[(size_t)b*T_ + tg], pt[tid]);
    }
}

__global__ void k_fill(float* __restrict__ out, float val) {
    out[blockIdx.x*256 + threadIdx.x] = val;
}

extern "C" void kernel_launch(void* const* d_in, const int* in_sizes, int n_in,
                              void* d_out, int out_size, void* d_ws, size_t ws_size,
                              hipStream_t stream) {
    const float* x       = (const float*)d_in[0];
    const float* fb_w    = (const float*)d_in[1];
    const float* conv0_w = (const float*)d_in[2];
    const float* conv0_b = (const float*)d_in[3];
    const float* bn0_g   = (const float*)d_in[4];
    const float* bn0_b   = (const float*)d_in[5];
    const float* dil_w   = (const float*)d_in[6];
    const float* dil_b   = (const float*)d_in[7];
    const float* pw_w    = (const float*)d_in[8];
    const float* pw_b    = (const float*)d_in[9];
    const float* bn_g    = (const float*)d_in[10];
    const float* bn_b    = (const float*)d_in[11];
    const float* up_w    = (const float*)d_in[12];
    const float* up_b    = (const float*)d_in[13];
    const float* sdict   = (const float*)d_in[14];
    float* out = (float*)d_out;
    char* ws = (char*)d_ws;

    // layout (bytes)
    const size_t R1   = 33554432;   // spec16 -> enc[0]
    const size_t R2   = 33554432;   // enc[1]  (enc = r1, 67MB contiguous)
    const size_t ACT  = 16777216;   // f16 [b][t][c]
    char* r1   = ws;
    char* actA = ws + R1 + R2;
    char* actB = actA + ACT;
    char* wreg = actB + ACT;
    _Float16* W7   = (_Float16*)wreg;                      // 7*16384
    _Float16* Wd   = W7 + 7*16384;                         // 7*3*16384
    _Float16* Wp   = Wd + 7*3*16384;                       // 7*16384
    _Float16* Wup  = Wp + 7*16384;                         // 65536
    _Float16* Wfb  = Wup + 65536;                          // 65536
    float* stats   = (float*)(Wfb + 65536);                // 8*2*128 floats
    const size_t TOTAL = R1 + R2 + 2*ACT
                       + (7*16384 + 7*3*16384 + 7*16384 + 65536 + 65536)*2 + 8*2*128*4;
    if (ws_size < TOTAL) {
        k_fill<<<(out_size+255)/256, 256, 0, stream>>>(out, 12345.0f);
        return;
    }
    _Float16* spec16 = (_Float16*)r1;
    _Float16* enc = (_Float16*)r1;            // [b][t][c], 67MB (spec16 dead after conv0)
    _Float16* At  = (_Float16*)(actA + 2097152);  // alias in actA (free after conv stack)

    // prep
    k_zero<<<(2048+255)/256, 256, 0, stream>>>(stats, 8*2*128);
    k_pw7<<<(7*16384+255)/256, 256, 0, stream>>>(conv0_w, W7);
    k_pwd<<<(7*3*16384+255)/256, 256, 0, stream>>>(dil_w, Wd);
    k_cast<<<(7*16384+255)/256, 256, 0, stream>>>(pw_w, Wp, 7*16384);
    k_cast<<<(65536+255)/256, 256, 0, stream>>>(up_w, Wup, 65536);
    k_cast<<<(65536+255)/256, 256, 0, stream>>>(fb_w, Wfb, 65536);

    // front: MFMA filter bank, direct time-major f16
    k_fbm<<<dim3(T_/128, B_), 256, 0, stream>>>(x, Wfb, spec16);
    k_cv<7,false,false,true,false,true><<<dim3(T_/128,1,B_), 256, 0, stream>>>(
        spec16, W7, conv0_b, nullptr, nullptr, nullptr, nullptr, nullptr,
        stats + 0, (_Float16*)actA, 1, CH_);

    const int DILS[7] = {1, 3, 9, 27, 81, 243, 1};
    _Float16* cur = (_Float16*)actA;
    _Float16* nxt = (_Float16*)actB;
    for (int i = 0; i < 7; ++i) {
        const float* gi = (i == 0) ? bn0_g : bn_g + (i-1)*CH_;
        const float* bi = (i == 0) ? bn0_b : bn_b + (i-1)*CH_;
        k_cv<3,true,true,true,false,true><<<dim3(T_/128,1,B_), 256, 0, stream>>>(
            cur, Wd + (size_t)i*3*CH_*CH_, dil_b + i*CH_, Wp + (size_t)i*CH_*CH_,
            pw_b + i*CH_, stats + i*256, gi, bi, stats + (i+1)*256, nxt, DILS[i], CH_);
        _Float16* sw = cur; cur = nxt; nxt = sw;
    }
    // cur == actB; actA free -> At alias valid; r1/r2 free for enc (both batches)

    k_tr_at<<<dim3(ATOM_/32, EC_/32), dim3(32,8), 0, stream>>>(sdict, At);
    // up-projection + relu -> enc[b][t][c] f16 (both batches)
    k_cv<1,true,false,false,true,false><<<dim3(T_/128,EC_/128,B_), 256, 0, stream>>>(
        cur, Wup, up_b, nullptr, nullptr,
        stats + 7*256, bn_g + 6*CH_, bn_b + 6*CH_, nullptr, enc, 1, EC_);

    // dictionary conv: zero out, then dbuf GEMM (XCD-swizzled) with fused anti-diag atomics
    k_zero<<<(B_*T_+255)/256, 256, 0, stream>>>(out, B_*T_);
    k_gemm<<<dim3(4096, B_), 256, 0, stream>>>(At, enc, out);
}